// Round 1
// baseline (224.552 us; speedup 1.0000x reference)
//
#include <hip/hip_runtime.h>

// Problem constants (fixed by the harness problem instance)
#define T_DIM 512
#define N_DIM 32
#define C_DIM 5000
#define S_DIM 128
// L = 2*S+1 = 257 states; lane l owns states 4l..4l+3; lane 63 also owns state 256.

#define NEGF (-1e30f)
#define LOG2E_F 1.4426950408889634f
#define LN2_F 0.6931471805599453f
#define PF_D 8  // prefetch depth (time steps ahead)

__device__ __forceinline__ float fexp2(float x) {
#if __has_builtin(__builtin_amdgcn_exp2f)
    return __builtin_amdgcn_exp2f(x);
#else
    return exp2f(x);
#endif
}
__device__ __forceinline__ float flog2(float x) {
#if __has_builtin(__builtin_amdgcn_logf)
    return __builtin_amdgcn_logf(x);
#else
    return log2f(x);
#endif
}

// log2-domain logsumexp
__device__ __forceinline__ float lse2(float a, float b) {
    float m = fmaxf(a, b);
    return m + flog2(fexp2(a - m) + fexp2(b - m));
}
__device__ __forceinline__ float lse3(float a, float b, float c) {
    float m = fmaxf(a, fmaxf(b, c));
    return m + flog2(fexp2(a - m) + fexp2(b - m) + fexp2(c - m));
}

// One wave (64 lanes) per batch element. States packed 4/lane (+state 256 on lane 63).
__global__ __launch_bounds__(64, 1) void ctc_scan_kernel(
        const float* __restrict__ lp,   // (T, N, C) log-probs
        const int* __restrict__ tgt,    // (N, S)
        const int* __restrict__ il,     // (N,)
        const int* __restrict__ tl,     // (N,)
        float* __restrict__ loss_out)   // (N,)
{
    const int n = blockIdx.x;
    const int lane = threadIdx.x;   // 0..63
    const int tlen = tl[n];
    const int ilen = il[n];

    const int* tgn = tgt + n * S_DIM;
    // odd-state classes for this lane: state 4l+1 -> tgt[2l], state 4l+3 -> tgt[2l+1]
    const int c1i = 2 * lane;
    const int c3i = 2 * lane + 1;
    const int c1 = tgn[c1i];
    const int c3 = tgn[c3i];
    const int c1prev = (c1i > 0) ? tgn[c1i - 1] : -1;
    const bool allow2_1 = (c1i > 0) && (c1 != c1prev);
    const bool allow2_3 = (c3 != c1);

    // validity: s < 2*tl+1  <=>  s <= 2*tl
    const int vmax = 2 * tlen;
    const int sb = lane << 2;
    const bool v0 = (sb    ) <= vmax;
    const bool v1 = (sb + 1) <= vmax;
    const bool v2 = (sb + 2) <= vmax;
    const bool v3 = (sb + 3) <= vmax;
    const bool v4 = (lane == 63) && (256 <= vmax);

    const size_t strideT = (size_t)N_DIM * C_DIM;
    const float* base = lp + (size_t)n * C_DIM;

    const int e1s = 2 * tlen;
    const int e2s = (2 * tlen - 1 > 0) ? (2 * tlen - 1) : 0;

    __shared__ float sh[2];

    // ---- t = 0 init ----
    float a0, a1, a2, a3, a4;
    {
        float lpb0 = base[0] * LOG2E_F;          // blank at t=0 (wave-uniform)
        float lp1 = base[c1] * LOG2E_F;          // lane 0's c1 == tgt[0]
        a0 = (lane == 0) ? lpb0 : NEGF;
        a1 = (lane == 0 && tlen > 0) ? lp1 : NEGF;
        a2 = NEGF; a3 = NEGF; a4 = NEGF;
        a0 = v0 ? a0 : NEGF;
        a1 = v1 ? a1 : NEGF;
    }
    if (ilen == 1) {
        if (sb     == e1s) sh[0] = a0;
        if (sb + 1 == e1s) sh[0] = a1;
        if (sb + 2 == e1s) sh[0] = a2;
        if (sb + 3 == e1s) sh[0] = a3;
        if (lane == 63 && e1s == 256) sh[0] = a4;
        if (sb     == e2s) sh[1] = a0;
        if (sb + 1 == e2s) sh[1] = a1;
        if (sb + 2 == e2s) sh[1] = a2;
        if (sb + 3 == e2s) sh[1] = a3;
    }

    // ---- prefetch ring for t = 1..PF_D ----
    float rb[PF_D], r1[PF_D], r3[PF_D];
#pragma unroll
    for (int j = 0; j < PF_D; ++j) {
        const float* bp = base + (size_t)(1 + j) * strideT;
        rb[j] = bp[0];
        r1[j] = bp[c1];
        r3[j] = bp[c3];
    }

    // ---- main recurrence t = 1..T-1 ----
    for (int tb = 1; tb < T_DIM; tb += PF_D) {
#pragma unroll
        for (int j = 0; j < PF_D; ++j) {
            const int t = tb + j;
            if (t < T_DIM) {
                // issue prefetch for t + PF_D
                float qb = 0.f, q1 = 0.f, q3 = 0.f;
                const int tp = t + PF_D;
                if (tp < T_DIM) {
                    const float* bp = base + (size_t)tp * strideT;
                    qb = bp[0];
                    q1 = bp[c1];
                    q3 = bp[c3];
                }
                // current step's (log2-scaled) log-probs
                const float pb = rb[j] * LOG2E_F;
                const float p1 = r1[j] * LOG2E_F;
                const float p3 = r3[j] * LOG2E_F;

                // neighbor alphas from lane-1 (old values)
                float am1 = __shfl_up(a3, 1);   // alpha[4l-1]
                float am2 = __shfl_up(a2, 1);   // alpha[4l-2]
                if (lane == 0) { am1 = NEGF; am2 = NEGF; }

                const float n0 = lse2(a0, am1);
                const float n1 = allow2_1 ? lse3(a1, a0, am1) : lse2(a1, a0);
                const float n2 = lse2(a2, a1);
                const float n3 = allow2_3 ? lse3(a3, a2, a1) : lse2(a3, a2);
                const float n4 = lse2(a4, a3);   // state 256 (lane 63 only meaningful)

                a0 = v0 ? (n0 + pb) : NEGF;
                a1 = v1 ? (n1 + p1) : NEGF;
                a2 = v2 ? (n2 + pb) : NEGF;
                a3 = v3 ? (n3 + p3) : NEGF;
                a4 = v4 ? (n4 + pb) : NEGF;

                if (t == ilen - 1) {
                    if (sb     == e1s) sh[0] = a0;
                    if (sb + 1 == e1s) sh[0] = a1;
                    if (sb + 2 == e1s) sh[0] = a2;
                    if (sb + 3 == e1s) sh[0] = a3;
                    if (lane == 63 && e1s == 256) sh[0] = a4;
                    if (sb     == e2s) sh[1] = a0;
                    if (sb + 1 == e2s) sh[1] = a1;
                    if (sb + 2 == e2s) sh[1] = a2;
                    if (sb + 3 == e2s) sh[1] = a3;
                }
                // rotate ring
                rb[j] = qb; r1[j] = q1; r3[j] = q3;
            }
        }
    }

    __syncthreads();
    if (lane == 0) {
        const float e1 = sh[0];
        const float e2 = (tlen > 0) ? sh[1] : NEGF;
        const float m = fmaxf(e1, e2);
        const float ll2 = m + flog2(fexp2(e1 - m) + fexp2(e2 - m)); // log2 domain
        const float ll = ll2 * LN2_F;                               // back to nats
        float loss = -ll;
        if (loss >= 1e29f) loss = 0.f;
        const int denom = (tlen > 1) ? tlen : 1;
        loss /= (float)denom;
        loss_out[n] = loss;
    }
}

__global__ __launch_bounds__(64, 1) void ctc_reduce_kernel(
        const float* __restrict__ loss, float* __restrict__ out)
{
    const int lane = threadIdx.x;
    float v = (lane < N_DIM) ? loss[lane] : 0.f;
#pragma unroll
    for (int off = 32; off > 0; off >>= 1) v += __shfl_down(v, off);
    if (lane == 0) out[0] = v / (float)N_DIM;
}

extern "C" void kernel_launch(void* const* d_in, const int* in_sizes, int n_in,
                              void* d_out, int out_size, void* d_ws, size_t ws_size,
                              hipStream_t stream) {
    const float* lp = (const float*)d_in[0];
    const int* tgt = (const int*)d_in[1];
    const int* il = (const int*)d_in[2];
    const int* tl = (const int*)d_in[3];
    float* out = (float*)d_out;
    float* losses = (float*)d_ws;

    ctc_scan_kernel<<<N_DIM, 64, 0, stream>>>(lp, tgt, il, tl, losses);
    ctc_reduce_kernel<<<1, 64, 0, stream>>>(losses, out);
}

// Round 2
// 136.344 us; speedup vs baseline: 1.6470x; 1.6470x over previous
//
#include <hip/hip_runtime.h>

// Problem constants
#define T_DIM 512
#define N_DIM 32
#define C_DIM 5000
#define S_DIM 128
#define STRIDE_T (N_DIM * C_DIM)     // 160000 elements between time steps
// L = 2*S+1 = 257 states; scan-wave lane l owns states 4l..4l+3 (+ state 256 on lane 63)

#define TC 64                         // time steps per LDS chunk
#define NCHUNK (T_DIM / TC)           // 8
#define LDW 132                       // LDS row stride (floats): slots 0..127 = tgt classes, 128 = blank
#define NLOADERS 192                  // 3 loader waves
#define NLOAD ((TC * 129) / NLOADERS) // 43 gathers per loader lane per chunk (exact)

#define NEGF (-1e30f)
#define LOG2E_F 1.4426950408889634f
#define LN2_F 0.6931471805599453f

__device__ __forceinline__ float fexp2(float x) {
#if __has_builtin(__builtin_amdgcn_exp2f)
    return __builtin_amdgcn_exp2f(x);
#else
    return exp2f(x);
#endif
}
__device__ __forceinline__ float flog2(float x) {
#if __has_builtin(__builtin_amdgcn_logf)
    return __builtin_amdgcn_logf(x);
#else
    return log2f(x);
#endif
}

// log2-domain logsumexp
__device__ __forceinline__ float lse2(float a, float b) {
    float m = fmaxf(a, b);
    return m + flog2(fexp2(a - m) + fexp2(b - m));
}
__device__ __forceinline__ float lse3(float a, float b, float c) {
    float m = fmaxf(a, fmaxf(b, c));   // -> v_max3_f32
    return m + flog2(fexp2(a - m) + fexp2(b - m) + fexp2(c - m));
}

// One block (4 waves) per batch element.
// Wave 0: sequential CTC alpha recurrence out of LDS.
// Waves 1-3: gather next chunk's log-probs (blank + 128 target classes per t) into LDS.
__global__ __launch_bounds__(256, 1) void ctc_fused_kernel(
        const float* __restrict__ lp,   // (T, N, C)
        const int* __restrict__ tgt,    // (N, S)
        const int* __restrict__ il,     // (N,)
        const int* __restrict__ tl,     // (N,)
        float* __restrict__ loss_out)   // (N,)
{
    const int n = blockIdx.x;
    const int tid = threadIdx.x;
    const int wid = tid >> 6;
    const int lane = tid & 63;

    const int tlen = tl[n];
    const int ilen = il[n];
    const int* tgn = tgt + n * S_DIM;
    const float* base = lp + (size_t)n * C_DIM;

    __shared__ float buf[2][TC * LDW];
    __shared__ float sh[2];

    // ---------------- loader setup (waves 1-3) ----------------
    int gof[NLOAD];   // gather element offset within chunk 0 (t*STRIDE_T + class)
    int wo[NLOAD];    // LDS write offset (t*LDW + k)
    if (wid != 0) {
        const int ltid = tid - 64;    // 0..191
#pragma unroll
        for (int j = 0; j < NLOAD; ++j) {
            const int i = ltid + NLOADERS * j;   // flat (t, k) id, k in [0,129)
            const int t = i / 129;
            const int k = i - 129 * t;
            const int cls = (k < 128) ? tgn[k] : 0;   // slot 128 = blank
            gof[j] = t * STRIDE_T + cls;
            wo[j] = t * LDW + k;
        }
        // prologue: fill chunk 0 into buf[0]
        float rg[NLOAD];
#pragma unroll
        for (int j = 0; j < NLOAD; ++j) rg[j] = base[(size_t)gof[j]];
#pragma unroll
        for (int j = 0; j < NLOAD; ++j) buf[0][wo[j]] = rg[j];
    }

    // ---------------- scan setup (wave 0) ----------------
    // lane l states: 4l (blank), 4l+1 (tgt[2l]), 4l+2 (blank), 4l+3 (tgt[2l+1])
    const int c1i = 2 * lane;
    const int c3i = 2 * lane + 1;
    bool allow2_1 = false, allow2_3 = false;
    if (wid == 0) {
        const int c1 = tgn[c1i];
        const int c3 = tgn[c3i];
        const int c1prev = (c1i > 0) ? tgn[c1i - 1] : -1;
        allow2_1 = (c1i > 0) && (c1 != c1prev);
        allow2_3 = (c3 != c1);
    }
    const int vmax = 2 * tlen;
    const int sb = lane << 2;
    const bool v0 = (sb    ) <= vmax;
    const bool v1 = (sb + 1) <= vmax;
    const bool v2 = (sb + 2) <= vmax;
    const bool v3 = (sb + 3) <= vmax;
    const bool v4 = (lane == 63) && (256 <= vmax);
    const int e1s = 2 * tlen;
    const int e2s = (2 * tlen - 1 > 0) ? (2 * tlen - 1) : 0;

    float a0 = NEGF, a1 = NEGF, a2 = NEGF, a3 = NEGF, a4 = NEGF;

    __syncthreads();   // chunk 0 ready

    for (int cc = 0; cc < NCHUNK; ++cc) {
        if (wid != 0) {
            // fill chunk cc+1 into buf[(cc+1)&1] (scan finished with it at barrier above)
            if (cc + 1 < NCHUNK) {
                const size_t coff = (size_t)(cc + 1) * TC * STRIDE_T;
                const float* bp = base + coff;
                float* dst = buf[(cc + 1) & 1];
                float rg[NLOAD];
#pragma unroll
                for (int j = 0; j < NLOAD; ++j) rg[j] = bp[(size_t)gof[j]];
#pragma unroll
                for (int j = 0; j < NLOAD; ++j) dst[wo[j]] = rg[j];
            }
        } else {
            const float* lb = buf[cc & 1];
            // one-step software-pipelined LDS reads
            float2 pq = *(const float2*)&lb[0 * LDW + 2 * lane];
            float pbv = lb[0 * LDW + 128];
#pragma unroll 8
            for (int tt = 0; tt < TC; ++tt) {
                const int ttn = (tt + 1 < TC) ? (tt + 1) : tt;
                const float2 pq_n = *(const float2*)&lb[ttn * LDW + 2 * lane];
                const float pbv_n = lb[ttn * LDW + 128];

                const int t = cc * TC + tt;
                const float pb = pbv  * LOG2E_F;
                const float p1 = pq.x * LOG2E_F;
                const float p3 = pq.y * LOG2E_F;

                if (t == 0) {
                    a0 = (lane == 0) ? pb : NEGF;
                    a1 = (lane == 0 && tlen > 0) ? p1 : NEGF;
                    a2 = NEGF; a3 = NEGF; a4 = NEGF;
                    a0 = v0 ? a0 : NEGF;
                    a1 = v1 ? a1 : NEGF;
                } else {
                    float am1 = __shfl_up(a3, 1);   // alpha[4l-1] (old)
                    if (lane == 0) am1 = NEGF;

                    const float n0 = lse2(a0, am1);
                    const float n1 = allow2_1 ? lse3(a1, a0, am1) : lse2(a1, a0);
                    const float n2 = lse2(a2, a1);
                    const float n3 = allow2_3 ? lse3(a3, a2, a1) : lse2(a3, a2);
                    const float n4 = lse2(a4, a3);  // state 256 (lane 63)

                    a0 = v0 ? (n0 + pb) : NEGF;
                    a1 = v1 ? (n1 + p1) : NEGF;
                    a2 = v2 ? (n2 + pb) : NEGF;
                    a3 = v3 ? (n3 + p3) : NEGF;
                    a4 = v4 ? (n4 + pb) : NEGF;
                }

                if (t == ilen - 1) {
                    if (sb     == e1s) sh[0] = a0;
                    if (sb + 1 == e1s) sh[0] = a1;
                    if (sb + 2 == e1s) sh[0] = a2;
                    if (sb + 3 == e1s) sh[0] = a3;
                    if (lane == 63 && e1s == 256) sh[0] = a4;
                    if (sb     == e2s) sh[1] = a0;
                    if (sb + 1 == e2s) sh[1] = a1;
                    if (sb + 2 == e2s) sh[1] = a2;
                    if (sb + 3 == e2s) sh[1] = a3;
                }

                pq = pq_n; pbv = pbv_n;
            }
        }
        __syncthreads();
    }

    if (tid == 0) {
        const float e1 = sh[0];
        const float e2 = (tlen > 0) ? sh[1] : NEGF;
        const float m = fmaxf(e1, e2);
        const float ll2 = m + flog2(fexp2(e1 - m) + fexp2(e2 - m)); // log2 domain
        const float ll = ll2 * LN2_F;                               // nats
        float loss = -ll;
        if (loss >= 1e29f) loss = 0.f;
        const int denom = (tlen > 1) ? tlen : 1;
        loss_out[n] = loss / (float)denom;
    }
}

__global__ __launch_bounds__(64, 1) void ctc_reduce_kernel(
        const float* __restrict__ loss, float* __restrict__ out)
{
    const int lane = threadIdx.x;
    float v = (lane < N_DIM) ? loss[lane] : 0.f;
#pragma unroll
    for (int off = 32; off > 0; off >>= 1) v += __shfl_down(v, off);
    if (lane == 0) out[0] = v / (float)N_DIM;
}

extern "C" void kernel_launch(void* const* d_in, const int* in_sizes, int n_in,
                              void* d_out, int out_size, void* d_ws, size_t ws_size,
                              hipStream_t stream) {
    const float* lp = (const float*)d_in[0];
    const int* tgt = (const int*)d_in[1];
    const int* il = (const int*)d_in[2];
    const int* tl = (const int*)d_in[3];
    float* out = (float*)d_out;
    float* losses = (float*)d_ws;

    ctc_fused_kernel<<<N_DIM, 256, 0, stream>>>(lp, tgt, il, tl, losses);
    ctc_reduce_kernel<<<1, 64, 0, stream>>>(losses, out);
}